// Round 5
// baseline (44.841 us; speedup 1.0000x reference)
//
#include <hip/hip_runtime.h>
#include <math.h>

// RoPE, X shape (N=32, D=128, L=8192) f32.
// Fused single kernel: each thread owns one (i, k4) pair -> computes 4
// sincos values ONCE, reuses across NN=16 batches. sincos lane-calls =
// 64*2048*2*4 = 1M (~4 us VALU across the kernel, hidden by TLP).
// Nontemporal stores keep the 134 MB write stream from evicting X from L3
// (R2 profile: half of X's reads already hit L3; protect that).
// Clang quirks (R3/R4): __builtin_nontemporal_store needs a NATIVE clang
// vector (ext_vector_type), and ext_vector elements are NOT addressable ->
// sincosf writes to scalar locals, then assemble the vector.
//
// Numerics (validated R1/R2, absmax 1.6e-2 vs 0.109 threshold):
//  - theta = f32(pow(10000.0, i/64.0) in double)  (correctly-rounded f32)
//  - angle = IEEE f32 product theta*k  (matches numpy broadcasting mult)
//  - sincosf = OCML full Payne-Hanek (angles reach ~7e7 rad; NO fast-math)

typedef float f32x4 __attribute__((ext_vector_type(4)));

#define N_BATCH 32
#define D_DIM   128
#define HALF    64
#define SEQ_L   8192
#define L_VEC4  (SEQ_L / 4)      // 2048 float4 per row
#define NN      16               // batches per thread
#define NGRP    (N_BATCH / NN)   // 2
#define TOTAL_THREADS (NGRP * HALF * L_VEC4)   // 262144 -> 1024 blocks

__global__ __launch_bounds__(256) void rope_fused(const f32x4* __restrict__ X,
                                                  f32x4* __restrict__ out) {
    int tid = blockIdx.x * blockDim.x + threadIdx.x;
    if (tid >= TOTAL_THREADS) return;
    int k4 = tid & (L_VEC4 - 1);
    int i  = (tid >> 11) & (HALF - 1);
    int g  = tid >> 17;              // 0..NGRP-1

    // theta_i = 10000^(i/64), correctly rounded to f32 via double pow.
    float theta = (float)pow(10000.0, (double)i * (1.0 / 64.0));

    float k0 = (float)(k4 * 4);
    float s0, c0, s1, c1, s2, c2, s3, c3;
    sincosf(theta * k0,          &s0, &c0);
    sincosf(theta * (k0 + 1.0f), &s1, &c1);
    sincosf(theta * (k0 + 2.0f), &s2, &c2);
    sincosf(theta * (k0 + 3.0f), &s3, &c3);
    f32x4 c = {c0, c1, c2, c3};
    f32x4 s = {s0, s1, s2, s3};

    int n0 = g * NN;
    #pragma unroll
    for (int t = 0; t < NN; ++t) {
        int n = n0 + t;
        int b1 = ((n * D_DIM + i) << 11) + k4;          // (n, i, k)
        int b2 = b1 + (HALF << 11);                     // (n, i+64, k)
        f32x4 x1 = X[b1];
        f32x4 x2 = X[b2];
        f32x4 o1 = c * x1 - s * x2;
        f32x4 o2 = s * x1 + c * x2;
        __builtin_nontemporal_store(o1, &out[b1]);
        __builtin_nontemporal_store(o2, &out[b2]);
    }
}

extern "C" void kernel_launch(void* const* d_in, const int* in_sizes, int n_in,
                              void* d_out, int out_size, void* d_ws, size_t ws_size,
                              hipStream_t stream) {
    const f32x4* X = (const f32x4*)d_in[0];
    f32x4* out     = (f32x4*)d_out;
    const int block = 256;
    rope_fused<<<TOTAL_THREADS / block, block, 0, stream>>>(X, out);
}